// Round 1
// baseline (1351.713 us; speedup 1.0000x reference)
//
#include <hip/hip_runtime.h>
#include <cstdint>
#include <math.h>

#define N_    8192
#define D_    256
#define TEMP_INV (1.0f/0.07f)
#define HARDK 10
#define RROWS 16
#define TJ    32
#define NT    256

// ---------------- Threefry-2x32, key = (0, 42), 20 rounds ----------------
// JAX partitionable layout: counter pair = (hi=0, lo=idx), output = x0 ^ x1.
__device__ __forceinline__ uint32_t rotl32(uint32_t x, int n) {
  return (x << n) | (x >> (32 - n));
}

__device__ uint32_t tf_bits(uint32_t idx) {
  uint32_t x0 = 0u;
  uint32_t x1 = idx;
  const uint32_t k0 = 0u, k1 = 42u;
  const uint32_t k2 = k0 ^ k1 ^ 0x1BD11BDAu;
  x0 += k0; x1 += k1;
#define TFR(r) { x0 += x1; x1 = rotl32(x1, r); x1 ^= x0; }
  TFR(13) TFR(15) TFR(26) TFR(6)
  x0 += k1; x1 += k2 + 1u;
  TFR(17) TFR(29) TFR(16) TFR(24)
  x0 += k2; x1 += k0 + 2u;
  TFR(13) TFR(15) TFR(26) TFR(6)
  x0 += k0; x1 += k1 + 3u;
  TFR(17) TFR(29) TFR(16) TFR(24)
  x0 += k1; x1 += k2 + 4u;
  TFR(13) TFR(15) TFR(26) TFR(6)
  x0 += k2; x1 += k0 + 5u;
#undef TFR
  return x0 ^ x1;
}

// ---------------- Kernel 1: per-row 1/max(||x||, 1e-12) ----------------
__global__ __launch_bounds__(64) void norm_kernel(const float* __restrict__ feats,
                                                  float* __restrict__ inv_norm) {
  const int i = blockIdx.x;
  const int lane = threadIdx.x;
  float4 v = reinterpret_cast<const float4*>(feats)[(size_t)i * (D_ / 4) + lane];
  float ss = v.x * v.x + v.y * v.y + v.z * v.z + v.w * v.w;
#pragma unroll
  for (int o = 32; o > 0; o >>= 1) ss += __shfl_down(ss, o);
  if (lane == 0) inv_norm[i] = 1.0f / fmaxf(sqrtf(ss), 1e-12f);
}

// ---------------- Kernel 2: 16-row strip: sim + top-k + gumbel ----------------
__global__ __launch_bounds__(NT) void strip_kernel(
    const float* __restrict__ feats, const int* __restrict__ labels,
    const float* __restrict__ inv_norm,
    float* __restrict__ li_out, int* __restrict__ valid_out) {
  __shared__ float zi[RROWS][260];
  __shared__ float tile[TJ][260];
  __shared__ float simt[RROWS][36];
  __shared__ int   lab_tile[TJ];

  const int tid = threadIdx.x;
  const int i0 = blockIdx.x * RROWS;

  // stage block rows (normalized) into zi
  for (int f = tid; f < RROWS * (D_ / 4); f += NT) {
    int row = f >> 6, c4 = f & 63;
    float4 v = reinterpret_cast<const float4*>(feats)[(size_t)(i0 + row) * (D_ / 4) + c4];
    float s = inv_norm[i0 + row];
    v.x *= s; v.y *= s; v.z *= s; v.w *= s;
    *reinterpret_cast<float4*>(&zi[row][c4 * 4]) = v;
  }

  // phase-2 (scan) identity: 16 scanners per row
  const int r2 = tid >> 4;
  const int s2 = tid & 15;
  const int gi = i0 + r2;
  const int lab_i = labels[gi];
  // phase-1 (compute) identity: col c1, rows rg*2 .. rg*2+1
  const int c1 = tid & 31;
  const int rg = tid >> 5;

  float tk[HARDK];
#pragma unroll
  for (int k = 0; k < HARDK; ++k) tk[k] = -INFINITY;
  uint32_t bkey = 0u; int bj = -1; float bsim = 0.f;

  __syncthreads();

  for (int t = 0; t < N_ / TJ; ++t) {
    const int j0 = t * TJ;
    // stage column tile (normalized)
    for (int f = tid; f < TJ * (D_ / 4); f += NT) {
      int row = f >> 6, c4 = f & 63;
      float4 v = reinterpret_cast<const float4*>(feats)[(size_t)(j0 + row) * (D_ / 4) + c4];
      float s = inv_norm[j0 + row];
      v.x *= s; v.y *= s; v.z *= s; v.w *= s;
      *reinterpret_cast<float4*>(&tile[row][c4 * 4]) = v;
    }
    if (tid < TJ) lab_tile[tid] = labels[j0 + tid];
    __syncthreads();

    // compute 16x32 sim tile, 2 rows per thread
    float acc0 = 0.f, acc1 = 0.f;
#pragma unroll 8
    for (int d = 0; d < D_; d += 4) {
      float4 b  = *reinterpret_cast<const float4*>(&tile[c1][d]);
      float4 a0 = *reinterpret_cast<const float4*>(&zi[rg * 2 + 0][d]);
      float4 a1 = *reinterpret_cast<const float4*>(&zi[rg * 2 + 1][d]);
      acc0 += a0.x * b.x + a0.y * b.y + a0.z * b.z + a0.w * b.w;
      acc1 += a1.x * b.x + a1.y * b.y + a1.z * b.z + a1.w * b.w;
    }
    simt[rg * 2 + 0][c1] = acc0;
    simt[rg * 2 + 1][c1] = acc1;
    __syncthreads();

    // scan: top-k over diff-label, threefry-argmax over same-label (excl. self)
#pragma unroll
    for (int k = 0; k < 2; ++k) {
      int c2 = s2 * 2 + k;
      int j  = j0 + c2;
      float sv = simt[r2][c2];
      int lj = lab_tile[c2];
      if (lj != lab_i) {
        if (sv > tk[0]) {
          tk[0] = sv;
#pragma unroll
          for (int p = 0; p < HARDK - 1; ++p)
            if (tk[p] > tk[p + 1]) { float tmp = tk[p]; tk[p] = tk[p + 1]; tk[p + 1] = tmp; }
        }
      } else if (j != gi) {
        uint32_t key = tf_bits((uint32_t)gi * (uint32_t)N_ + (uint32_t)j) >> 9;
        if (bj < 0 || key > bkey) { bkey = key; bj = j; bsim = sv; }  // ascending j: > keeps first max
      }
    }
    __syncthreads();
  }

  // ---- merge (scratch aliased onto tile buffer; loop is done) ----
  float* topk_all = &tile[0][0];                        // 16*16*10 floats = 10240 B
  int*   gkey_all = (int*)(topk_all + RROWS * 16 * HARDK);
  int*   gj_all   = gkey_all + RROWS * 16;
  float* gs_all   = (float*)(gj_all + RROWS * 16);

  {
    int base = r2 * 16 + s2;
#pragma unroll
    for (int k = 0; k < HARDK; ++k) topk_all[base * HARDK + k] = tk[k];
    gkey_all[base] = (int)bkey;
    gj_all[base]   = bj;
    gs_all[base]   = bsim;
  }
  __syncthreads();

  if (tid < RROWS) {
    const int r = tid;
    float arr[HARDK];
#pragma unroll
    for (int k = 0; k < HARDK; ++k) arr[k] = -INFINITY;
    for (int s = 0; s < 16; ++s) {
      for (int k = 0; k < HARDK; ++k) {
        float v = topk_all[(r * 16 + s) * HARDK + k];
        if (v > arr[0]) {
          arr[0] = v;
#pragma unroll
          for (int p = 0; p < HARDK - 1; ++p)
            if (arr[p] > arr[p + 1]) { float tmp = arr[p]; arr[p] = arr[p + 1]; arr[p + 1] = tmp; }
        }
      }
    }
    uint32_t BK = 0u; int BJ = -1; float BS = 0.f;
    for (int s = 0; s < 16; ++s) {
      int jj = gj_all[r * 16 + s];
      if (jj < 0) continue;
      uint32_t kk = (uint32_t)gkey_all[r * 16 + s];
      if (BJ < 0 || kk > BK || (kk == BK && jj < BJ)) { BK = kk; BJ = jj; BS = gs_all[r * 16 + s]; }
    }
    bool any_diff = (arr[HARDK - 1] > -1e37f);
    bool valid = (BJ >= 0) && any_diff;
    float li = 0.f;
    if (valid) {
      float num = expf(BS * TEMP_INV);
      float den = num;
#pragma unroll
      for (int k = 0; k < HARDK; ++k) {
        float v = arr[k];
        if (v > -1e37f) den += expf(v * TEMP_INV);
      }
      float ratio = fmaxf(num / fmaxf(den, 1e-8f), 1e-8f);
      li = -logf(ratio);
    }
    li_out[i0 + r] = li;
    valid_out[i0 + r] = valid ? 1 : 0;
  }
}

// ---------------- Kernel 3: final reduction ----------------
__global__ __launch_bounds__(256) void reduce_kernel(const float* __restrict__ li,
                                                     const int* __restrict__ valid,
                                                     float* __restrict__ out) {
  __shared__ float ssum[4];
  __shared__ int   scnt[4];
  float s = 0.f; int c = 0;
  for (int i = threadIdx.x; i < N_; i += 256) { s += li[i]; c += valid[i]; }
#pragma unroll
  for (int o = 32; o > 0; o >>= 1) { s += __shfl_down(s, o); c += __shfl_down(c, o); }
  if ((threadIdx.x & 63) == 0) { ssum[threadIdx.x >> 6] = s; scnt[threadIdx.x >> 6] = c; }
  __syncthreads();
  if (threadIdx.x == 0) {
    float S = 0.f; int C = 0;
    for (int w = 0; w < 4; ++w) { S += ssum[w]; C += scnt[w]; }
    out[0] = S / (float)(C > 0 ? C : 1);
  }
}

extern "C" void kernel_launch(void* const* d_in, const int* in_sizes, int n_in,
                              void* d_out, int out_size, void* d_ws, size_t ws_size,
                              hipStream_t stream) {
  const float* feats  = (const float*)d_in[0];
  const int*   labels = (const int*)d_in[1];
  float* out = (float*)d_out;

  float* inv_norm  = (float*)d_ws;          // 8192 f
  float* li_arr    = inv_norm + N_;         // 8192 f
  int*   valid_arr = (int*)(li_arr + N_);   // 8192 i

  hipLaunchKernelGGL(norm_kernel, dim3(N_), dim3(64), 0, stream, feats, inv_norm);
  hipLaunchKernelGGL(strip_kernel, dim3(N_ / RROWS), dim3(NT), 0, stream,
                     feats, labels, inv_norm, li_arr, valid_arr);
  hipLaunchKernelGGL(reduce_kernel, dim3(1), dim3(256), 0, stream, li_arr, valid_arr, out);
}

// Round 2
// 121.364 us; speedup vs baseline: 11.1376x; 11.1376x over previous
//
#include <hip/hip_runtime.h>
#include <cstdint>
#include <math.h>

#define N_     8192
#define D_     256
#define NLBL   128
#define TEMP_INV 14.285714285714286f
#define HARDK  10

#define RB     128              // rows per block (4 waves x 32)
#define NCHUNK 8
#define CHUNK  (N_ / NCHUNK)    // 1024 cols per block
#define TILES  (CHUNK / 32)     // 32
#define GCAP   256              // per-label list capacity

typedef __attribute__((ext_vector_type(8)))  short bf16x8;
typedef __attribute__((ext_vector_type(16))) float f32x16;

// ---------------- Threefry-2x32, key=(0,42): exact-match validated in R1 ----------------
__device__ __forceinline__ uint32_t rotl32(uint32_t x, int n) {
  return (x << n) | (x >> (32 - n));
}
__device__ uint32_t tf_bits(uint32_t idx) {
  uint32_t x0 = 0u, x1 = idx;
  const uint32_t k0 = 0u, k1 = 42u;
  const uint32_t k2 = k0 ^ k1 ^ 0x1BD11BDAu;
  x0 += k0; x1 += k1;
#define TFR(r) { x0 += x1; x1 = rotl32(x1, r); x1 ^= x0; }
  TFR(13) TFR(15) TFR(26) TFR(6)
  x0 += k1; x1 += k2 + 1u;
  TFR(17) TFR(29) TFR(16) TFR(24)
  x0 += k2; x1 += k0 + 2u;
  TFR(13) TFR(15) TFR(26) TFR(6)
  x0 += k0; x1 += k1 + 3u;
  TFR(17) TFR(29) TFR(16) TFR(24)
  x0 += k1; x1 += k2 + 4u;
  TFR(13) TFR(15) TFR(26) TFR(6)
  x0 += k2; x1 += k0 + 5u;
#undef TFR
  return x0 ^ x1;
}

__device__ __forceinline__ unsigned short f2bf(float x) {  // RNE
  uint32_t b = __float_as_uint(x);
  return (unsigned short)((b + 0x7FFFu + ((b >> 16) & 1u)) >> 16);
}

// ---------------- K1: inv_norm + bf16 z ----------------
__global__ __launch_bounds__(64) void prep_kernel(const float* __restrict__ feats,
                                                  float* __restrict__ inv_norm,
                                                  unsigned short* __restrict__ zbf) {
  const int i = blockIdx.x, l = threadIdx.x;
  float4 v = ((const float4*)feats)[(size_t)i * 64 + l];
  float ss = v.x * v.x + v.y * v.y + v.z * v.z + v.w * v.w;
#pragma unroll
  for (int o = 32; o; o >>= 1) ss += __shfl_xor(ss, o);
  float inv = 1.0f / fmaxf(sqrtf(ss), 1e-12f);
  if (l == 0) inv_norm[i] = inv;
  uint2 p;
  p.x = (uint32_t)f2bf(v.x * inv) | ((uint32_t)f2bf(v.y * inv) << 16);
  p.y = (uint32_t)f2bf(v.z * inv) | ((uint32_t)f2bf(v.w * inv) << 16);
  ((uint2*)zbf)[(size_t)i * 64 + l] = p;
}

// ---------------- K2: per-label column bitmask + group list + count ----------------
__global__ __launch_bounds__(256) void group_kernel(const int* __restrict__ labels,
                                                    uint32_t* __restrict__ mask_g,
                                                    int* __restrict__ glist,
                                                    int* __restrict__ cnt_g) {
  const int b = blockIdx.x;
  const int tid = threadIdx.x, lane = tid & 63, wv = tid >> 6;
  __shared__ int lcnt;
  if (tid == 0) lcnt = 0;
  __syncthreads();
  for (int it = 0; it < N_; it += 256) {
    int col = it + tid;
    bool pred = (labels[col] == b);
    unsigned long long m = __ballot(pred);
    if (lane == 0) {
      int w0 = (it + wv * 64) >> 5;
      mask_g[b * 256 + w0]     = (uint32_t)m;
      mask_g[b * 256 + w0 + 1] = (uint32_t)(m >> 32);
    }
    if (pred) {
      int p = atomicAdd(&lcnt, 1);
      if (p < GCAP) glist[b * GCAP + p] = col;
    }
  }
  __syncthreads();
  if (tid == 0) cnt_g[b] = lcnt;
}

// ---------------- K3: positive pick (threefry argmax) + fp32 pos cosine ----------------
__global__ __launch_bounds__(256) void pos_kernel(const float* __restrict__ feats,
                                                  const int* __restrict__ labels,
                                                  const float* __restrict__ inv_norm,
                                                  const int* __restrict__ glist,
                                                  const int* __restrict__ cnt_g,
                                                  float* __restrict__ poscos,
                                                  int* __restrict__ validrow) {
  const int row = blockIdx.x * 4 + (threadIdx.x >> 6);
  const int lane = threadIdx.x & 63;
  const int lab = labels[row];
  const int c = cnt_g[lab];
  const int n = c < GCAP ? c : GCAP;
  uint32_t bk = 0u; int bj = -1;
  for (int e = lane; e < n; e += 64) {
    int j = glist[lab * GCAP + e];
    if (j != row) {
      uint32_t key = tf_bits((uint32_t)row * (uint32_t)N_ + (uint32_t)j) >> 9;
      if (bj < 0 || key > bk || (key == bk && j < bj)) { bk = key; bj = j; }
    }
  }
#pragma unroll
  for (int o = 32; o; o >>= 1) {
    uint32_t ok = __shfl_xor(bk, o);
    int oj = __shfl_xor(bj, o);
    if (oj >= 0 && (bj < 0 || ok > bk || (ok == bk && oj < bj))) { bk = ok; bj = oj; }
  }
  float pc = 0.f;
  if (bj >= 0) {
    float4 a = ((const float4*)feats)[(size_t)row * 64 + lane];
    float4 b = ((const float4*)feats)[(size_t)bj * 64 + lane];
    float p = a.x * b.x + a.y * b.y + a.z * b.z + a.w * b.w;
#pragma unroll
    for (int o = 32; o; o >>= 1) p += __shfl_xor(p, o);
    pc = p * inv_norm[row] * inv_norm[bj];
  }
  if (lane == 0) {
    poscos[row] = pc;
    validrow[row] = (bj >= 0 && c < N_) ? 1 : 0;
  }
}

// ---------------- K4: MFMA sim tiles + in-register per-row top-10 ----------------
__device__ __forceinline__ void stage_tile(const unsigned short* zbf, char (*AbK)[1024],
                                           int colT, int wid, int l, int kg) {
  const char* base = (const char*)zbf + ((size_t)(colT + (l & 31)) * (D_ * 2) + kg * 16);
#pragma unroll
  for (int q = 0; q < 4; ++q) {
    const int kk = wid * 4 + q;
    __builtin_amdgcn_global_load_lds(
        (const __attribute__((address_space(1))) void*)(base + kk * 32),
        (__attribute__((address_space(3))) void*)(&AbK[kk][0]), 16, 0, 0);
  }
}

__global__ __launch_bounds__(256) void simscan_kernel(const unsigned short* __restrict__ zbf,
                                                      const int* __restrict__ labels,
                                                      const uint32_t* __restrict__ mask_g,
                                                      float* __restrict__ part) {
  __shared__ char Ab[2][16][1024];       // [buf][kk][lane*16]
  __shared__ uint32_t lm[NLBL * 33];     // padded label-mask slice

  const int tid = threadIdx.x;
  const int l = tid & 63, wid = tid >> 6;
  const int kg = l >> 5;
  const int bx = blockIdx.x;
  const int rc = bx & 63, cc = bx >> 6;
  const int row0 = rc * RB;
  const int col0 = cc * CHUNK;

  for (int idx = tid; idx < NLBL * 32; idx += 256) {
    int lab = idx >> 5, wd = idx & 31;
    lm[lab * 33 + wd] = mask_g[lab * 256 + (col0 >> 5) + wd];
  }

  const int rowW = row0 + wid * 32 + (l & 31);
  const int lab_i = labels[rowW];

  // B fragments: 16 K-steps of this lane's row (64 VGPRs)
  bf16x8 bfrag[16];
  {
    const bf16x8* zr = (const bf16x8*)(zbf + (size_t)rowW * D_);
#pragma unroll
    for (int kk = 0; kk < 16; ++kk) bfrag[kk] = zr[kk * 2 + kg];
  }

  float dk[HARDK];
#pragma unroll
  for (int k = 0; k < HARDK; ++k) dk[k] = -INFINITY;

  stage_tile(zbf, Ab[0], col0, wid, l, kg);
  __syncthreads();

  int buf = 0;
  for (int t = 0; t < TILES; ++t) {
    if (t + 1 < TILES) stage_tile(zbf, Ab[buf ^ 1], col0 + (t + 1) * 32, wid, l, kg);

    f32x16 acc;
#pragma unroll
    for (int r = 0; r < 16; ++r) acc[r] = 0.f;
#pragma unroll
    for (int kk = 0; kk < 16; ++kk) {
      bf16x8 a = *(const bf16x8*)&Ab[buf][kk][l * 16];
      acc = __builtin_amdgcn_mfma_f32_32x32x16_bf16(a, bfrag[kk], acc, 0, 0, 0);
    }

    // scan: lane owns row i = rowW; acc[r] = sim(i, col0+t*32 + m(r)), m = (r&3)+8*(r>>2)+4*kg
    uint32_t wsh = lm[lab_i * 33 + t] >> (kg * 4);
#pragma unroll
    for (int r = 0; r < 16; ++r) {
      const int cpos = (r & 3) + 8 * (r >> 2);
      float c = (wsh & (1u << cpos)) ? -INFINITY : acc[r];
#pragma unroll
      for (int p = 0; p < HARDK; ++p) {
        float hi = fmaxf(dk[p], c);
        c = fminf(dk[p], c);
        dk[p] = hi;
      }
    }
    __syncthreads();
    buf ^= 1;
  }

  // partial list out, [list][row] layout for coalescing
#pragma unroll
  for (int k = 0; k < HARDK; ++k)
    part[(size_t)((cc * 2 + kg) * HARDK + k) * N_ + rowW] = dk[k];
}

// ---------------- K5: merge partial top-10 lists + loss ----------------
__global__ __launch_bounds__(256) void merge_kernel(const float* __restrict__ part,
                                                    const float* __restrict__ poscos,
                                                    const int* __restrict__ validrow,
                                                    float* __restrict__ li,
                                                    int* __restrict__ valid) {
  const int row = blockIdx.x * 256 + threadIdx.x;
  float dk[HARDK];
#pragma unroll
  for (int k = 0; k < HARDK; ++k) dk[k] = -INFINITY;
  for (int s = 0; s < NCHUNK * 2; ++s) {
#pragma unroll
    for (int k = 0; k < HARDK; ++k) {
      float c = part[(size_t)(s * HARDK + k) * N_ + row];
#pragma unroll
      for (int p = 0; p < HARDK; ++p) {
        float hi = fmaxf(dk[p], c);
        c = fminf(dk[p], c);
        dk[p] = hi;
      }
    }
  }
  float num = expf(poscos[row] * TEMP_INV);
  float den = num;
#pragma unroll
  for (int k = 0; k < HARDK; ++k) den += expf(dk[k] * TEMP_INV);
  bool v = (validrow[row] != 0) && (dk[0] > -1e37f);
  float L = v ? -logf(fmaxf(num / fmaxf(den, 1e-8f), 1e-8f)) : 0.f;
  li[row] = L;
  valid[row] = v ? 1 : 0;
}

// ---------------- K6: final mean ----------------
__global__ __launch_bounds__(256) void reduce_kernel(const float* __restrict__ li,
                                                     const int* __restrict__ valid,
                                                     float* __restrict__ out) {
  __shared__ float ssum[4];
  __shared__ int scnt[4];
  float s = 0.f; int c = 0;
  for (int i = threadIdx.x; i < N_; i += 256) { s += li[i]; c += valid[i]; }
#pragma unroll
  for (int o = 32; o; o >>= 1) { s += __shfl_down(s, o); c += __shfl_down(c, o); }
  if ((threadIdx.x & 63) == 0) { ssum[threadIdx.x >> 6] = s; scnt[threadIdx.x >> 6] = c; }
  __syncthreads();
  if (threadIdx.x == 0) {
    float S = 0.f; int C = 0;
    for (int w = 0; w < 4; ++w) { S += ssum[w]; C += scnt[w]; }
    out[0] = S / (float)(C > 0 ? C : 1);
  }
}

extern "C" void kernel_launch(void* const* d_in, const int* in_sizes, int n_in,
                              void* d_out, int out_size, void* d_ws, size_t ws_size,
                              hipStream_t stream) {
  const float* feats  = (const float*)d_in[0];
  const int*   labels = (const int*)d_in[1];
  float* out = (float*)d_out;

  char* w = (char*)d_ws;
  unsigned short* zbf = (unsigned short*)w;  w += (size_t)N_ * D_ * 2;        // 4 MB
  float* inv_norm = (float*)w;               w += (size_t)N_ * 4;
  uint32_t* mask_g = (uint32_t*)w;           w += (size_t)NLBL * 256 * 4;     // 128 KB
  int* glist = (int*)w;                      w += (size_t)NLBL * GCAP * 4;    // 128 KB
  int* cnt_g = (int*)w;                      w += (size_t)NLBL * 4;
  float* poscos = (float*)w;                 w += (size_t)N_ * 4;
  int* validrow = (int*)w;                   w += (size_t)N_ * 4;
  float* part = (float*)w;                   w += (size_t)NCHUNK * 2 * HARDK * N_ * 4;  // 5.24 MB
  float* li_arr = (float*)w;                 w += (size_t)N_ * 4;
  int* valid_arr = (int*)w;                  w += (size_t)N_ * 4;

  hipLaunchKernelGGL(prep_kernel, dim3(N_), dim3(64), 0, stream, feats, inv_norm, zbf);
  hipLaunchKernelGGL(group_kernel, dim3(NLBL), dim3(256), 0, stream, labels, mask_g, glist, cnt_g);
  hipLaunchKernelGGL(pos_kernel, dim3(N_ / 4), dim3(256), 0, stream,
                     feats, labels, inv_norm, glist, cnt_g, poscos, validrow);
  hipLaunchKernelGGL(simscan_kernel, dim3(64 * NCHUNK), dim3(256), 0, stream,
                     zbf, labels, mask_g, part);
  hipLaunchKernelGGL(merge_kernel, dim3(N_ / 256), dim3(256), 0, stream,
                     part, poscos, validrow, li_arr, valid_arr);
  hipLaunchKernelGGL(reduce_kernel, dim3(1), dim3(256), 0, stream, li_arr, valid_arr, out);
}